// Round 1
// baseline (209.711 us; speedup 1.0000x reference)
//
#include <hip/hip_runtime.h>
#include <hip/hip_bf16.h>

#define CCH 256
#define HEADS 4

// ---------------- Kernel 1: global average pool -> node features ----------------
// grid: 8192 blocks (b*256+c), 256 threads. Each block reduces three 4096-float rows.
__global__ __launch_bounds__(256) void pool_kernel(
    const float* __restrict__ xf, const float* __restrict__ rgb,
    const float* __restrict__ dep, const float* __restrict__ tok,
    float* __restrict__ nodes /* [32][4][256] */)
{
    const int bc = blockIdx.x;          // 0..8191
    const int b  = bc >> 8, c = bc & 255;
    const int t  = threadIdx.x;
    const size_t base = (size_t)bc * 4096;
    const float4* xf4 = (const float4*)(xf + base);
    const float4* rg4 = (const float4*)(rgb + base);
    const float4* dp4 = (const float4*)(dep + base);
    float s0 = 0.f, s1 = 0.f, s2 = 0.f;
#pragma unroll
    for (int i = 0; i < 4; ++i) {
        float4 a = xf4[t + 256 * i];
        float4 r = rg4[t + 256 * i];
        float4 d = dp4[t + 256 * i];
        s0 += a.x + a.y + a.z + a.w;
        s1 += r.x + r.y + r.z + r.w;
        s2 += d.x + d.y + d.z + d.w;
    }
#pragma unroll
    for (int off = 32; off; off >>= 1) {
        s0 += __shfl_down(s0, off, 64);
        s1 += __shfl_down(s1, off, 64);
        s2 += __shfl_down(s2, off, 64);
    }
    __shared__ float sc[4][3];
    const int wave = t >> 6, lane = t & 63;
    if (lane == 0) { sc[wave][0] = s0; sc[wave][1] = s1; sc[wave][2] = s2; }
    __syncthreads();
    if (t == 0) {
        const float inv = 1.f / 4096.f;
        float f = (sc[0][0] + sc[1][0] + sc[2][0] + sc[3][0]) * inv;
        float r = (sc[0][1] + sc[1][1] + sc[2][1] + sc[3][1]) * inv;
        float d = (sc[0][2] + sc[1][2] + sc[2][2] + sc[3][2]) * inv;
        float* nb = nodes + (size_t)b * 4 * CCH;
        nb[0 * CCH + c] = tok[c];   // token node
        nb[1 * CCH + c] = f;        // x_ful pooled
        nb[2 * CCH + c] = r;        // rgb pooled
        nb[3 * CCH + c] = d;        // dep pooled
    }
}

// ---------------- Kernel 2: 2x (GATConv + residual + LN + ReLU), output gate ----------------
// grid: 32 blocks (batch), 1024 threads: t = h*256 + c.
__global__ __launch_bounds__(1024) void gat_kernel(
    const float* __restrict__ nodes, float* __restrict__ scale,
    const float* __restrict__ W0, const float* __restrict__ as0,
    const float* __restrict__ ad0, const float* __restrict__ b0,
    const float* __restrict__ g0, const float* __restrict__ be0,
    const float* __restrict__ W1, const float* __restrict__ as1,
    const float* __restrict__ ad1, const float* __restrict__ b1,
    const float* __restrict__ g1, const float* __restrict__ be1)
{
    const int t = threadIdx.x;          // 0..1023
    const int b = blockIdx.x;
    const int h = t >> 8, c = t & 255;

    __shared__ float gl[4][CCH];        // node features
    __shared__ float xp[4][HEADS * CCH];// xp[n][h*256+c] (also reused for head sums)
    __shared__ float red2[16][2];
    __shared__ float es[4][4], ed[4][4];      // [n][h]
    __shared__ float alpha_s[4][4][4];        // [d][h][j]
    __shared__ float mu_s[4], rstd_s[4];

    gl[t >> 8][t & 255] = nodes[(size_t)b * 1024 + t];
    __syncthreads();

    for (int layer = 0; layer < 2; ++layer) {
        const float* W  = layer ? W1  : W0;
        const float* As = layer ? as1 : as0;
        const float* Ad = layer ? ad1 : ad0;
        const float* Bi = layer ? b1  : b0;
        const float* Ga = layer ? g1  : g0;
        const float* Be = layer ? be1 : be0;

        // ---- xp = x @ W : thread t owns column t (= h*256+c) for all 4 nodes
        float a0 = 0.f, a1 = 0.f, a2 = 0.f, a3 = 0.f;
#pragma unroll 4
        for (int k = 0; k < 256; ++k) {
            float w = W[k * 1024 + t];
            a0 += gl[0][k] * w;
            a1 += gl[1][k] * w;
            a2 += gl[2][k] * w;
            a3 += gl[3][k] * w;
        }
        xp[0][t] = a0; xp[1][t] = a1; xp[2][t] = a2; xp[3][t] = a3;
        __syncthreads();

        // ---- attention logits: e_src[n][h], e_dst[n][h]
        const float av = As[t];   // a_src[h][c] flat == t
        const float dv = Ad[t];
#pragma unroll
        for (int n = 0; n < 4; ++n) {
            float x = xp[n][t];
            float vs = x * av, vd = x * dv;
#pragma unroll
            for (int off = 32; off; off >>= 1) {
                vs += __shfl_down(vs, off, 64);
                vd += __shfl_down(vd, off, 64);
            }
            if ((t & 63) == 0) { red2[t >> 6][0] = vs; red2[t >> 6][1] = vd; }
            __syncthreads();
            if (t < 4) {   // t = head group
                es[n][t] = red2[t*4][0] + red2[t*4+1][0] + red2[t*4+2][0] + red2[t*4+3][0];
                ed[n][t] = red2[t*4][1] + red2[t*4+1][1] + red2[t*4+2][1] + red2[t*4+3][1];
            }
            __syncthreads();
        }

        // ---- per-destination segment softmax (16 threads: d*4+h)
        if (t < 16) {
            const int d = t >> 2, hh = t & 3;
            const int cnt[4]        = {4, 3, 3, 3};
            const int srcs[4][4]    = {{1,2,3,0},{2,3,1,0},{1,3,2,0},{1,2,3,0}};
            float v[4];
            float m = -1e30f;
            const int n = cnt[d];
            for (int j = 0; j < n; ++j) {
                float e = es[srcs[d][j]][hh] + ed[d][hh];
                e = (e >= 0.f) ? e : 0.2f * e;         // leaky_relu 0.2
                v[j] = e; m = fmaxf(m, e);
            }
            float den = 0.f;
            for (int j = 0; j < n; ++j) { v[j] = expf(v[j] - m); den += v[j]; }
            float inv = 1.f / den;
            for (int j = 0; j < n; ++j) alpha_s[d][hh][j] = v[j] * inv;
            for (int j = n; j < 4; ++j) alpha_s[d][hh][j] = 0.f;
        }
        __syncthreads();

        // ---- aggregate messages: per-thread (h,c), all 4 dst nodes
        float ms[4];
        {
            const int srcs[4][4] = {{1,2,3,0},{2,3,1,0},{1,3,2,0},{1,2,3,0}};
#pragma unroll
            for (int d = 0; d < 4; ++d) {
                float s = 0.f;
#pragma unroll
                for (int j = 0; j < 4; ++j)
                    s += alpha_s[d][h][j] * xp[srcs[d][j]][t];
                ms[d] = s;
            }
        }
        __syncthreads();
#pragma unroll
        for (int d = 0; d < 4; ++d) xp[d][t] = ms[d];   // xp now holds per-head sums
        __syncthreads();

        // ---- head mean + bias + residual + LayerNorm + ReLU; thread t = (d = t>>8, c)
        const int d = t >> 8;
        float o = 0.25f * (xp[d][c] + xp[d][256 + c] + xp[d][512 + c] + xp[d][768 + c]) + Bi[c];
        float gv = o + gl[d][c];                        // residual
        float vs = gv, vq = gv * gv;
#pragma unroll
        for (int off = 32; off; off >>= 1) {
            vs += __shfl_down(vs, off, 64);
            vq += __shfl_down(vq, off, 64);
        }
        if ((t & 63) == 0) { red2[t >> 6][0] = vs; red2[t >> 6][1] = vq; }
        __syncthreads();
        if (t < 4) {
            float s = red2[t*4][0] + red2[t*4+1][0] + red2[t*4+2][0] + red2[t*4+3][0];
            float q = red2[t*4][1] + red2[t*4+1][1] + red2[t*4+2][1] + red2[t*4+3][1];
            float mu  = s * (1.f / 256.f);
            float var = q * (1.f / 256.f) - mu * mu;
            mu_s[t]   = mu;
            rstd_s[t] = rsqrtf(var + 1e-5f);
        }
        __syncthreads();
        float y = (gv - mu_s[d]) * rstd_s[d] * Ga[c] + Be[c];
        y = fmaxf(y, 0.f);
        gl[d][c] = y;
        __syncthreads();
    }

    // ---- output gate from token node: scale = 1 + sigmoid(g[b,0,c])
    if (t < 256) {
        float x = gl[0][t];
        float sg = 1.f / (1.f + expf(-x));
        scale[(size_t)b * CCH + t] = 1.f + sg;
    }
}

// ---------------- Kernel 3: out = x_ful * (1 + sigmoid) ----------------
__global__ __launch_bounds__(256) void apply_kernel(
    const float* __restrict__ xf, const float* __restrict__ scale,
    float* __restrict__ out, int total4)
{
    int idx = blockIdx.x * 256 + threadIdx.x;
    const int stride = gridDim.x * 256;
    for (; idx < total4; idx += stride) {
        float4 v = ((const float4*)xf)[idx];
        const int bc = idx >> 10;          // 1024 float4 per (b,c) row
        const float s = scale[bc];
        float4 o;
        o.x = v.x * s; o.y = v.y * s; o.z = v.z * s; o.w = v.w * s;
        ((float4*)out)[idx] = o;
    }
}

extern "C" void kernel_launch(void* const* d_in, const int* in_sizes, int n_in,
                              void* d_out, int out_size, void* d_ws, size_t ws_size,
                              hipStream_t stream) {
    const float* x_ful = (const float*)d_in[0];
    const float* rgb   = (const float*)d_in[1];
    const float* dep   = (const float*)d_in[2];
    const float* tok   = (const float*)d_in[3];
    const float* W0  = (const float*)d_in[4];
    const float* as0 = (const float*)d_in[5];
    const float* ad0 = (const float*)d_in[6];
    const float* b0  = (const float*)d_in[7];
    const float* g0  = (const float*)d_in[8];
    const float* be0 = (const float*)d_in[9];
    const float* W1  = (const float*)d_in[10];
    const float* as1 = (const float*)d_in[11];
    const float* ad1 = (const float*)d_in[12];
    const float* b1  = (const float*)d_in[13];
    const float* g1  = (const float*)d_in[14];
    const float* be1 = (const float*)d_in[15];

    float* nodes = (float*)d_ws;                          // [32][4][256] = 128 KB
    float* scale = (float*)((char*)d_ws + 32 * 4 * CCH * sizeof(float)); // [32][256]
    float* out   = (float*)d_out;

    const int B = 32;
    pool_kernel<<<B * CCH, 256, 0, stream>>>(x_ful, rgb, dep, tok, nodes);
    gat_kernel<<<B, 1024, 0, stream>>>(nodes, scale,
                                       W0, as0, ad0, b0, g0, be0,
                                       W1, as1, ad1, b1, g1, be1);
    const int total4 = B * CCH * 64 * 64 / 4;             // 8,388,608 float4
    apply_kernel<<<2048, 256, 0, stream>>>(x_ful, scale, out, total4);
}

// Round 2
// 166.536 us; speedup vs baseline: 1.2593x; 1.2593x over previous
//
#include <hip/hip_runtime.h>
#include <hip/hip_bf16.h>

#define CCH 256
#define HEADS 4

typedef float f4 __attribute__((ext_vector_type(4)));

// ---------------- Kernel 1a: pool rgb + dep (nontemporal loads) ----------------
// wave-per-row: 64 lanes x 16 float4 = 4096 floats. grid = 16384 rows / 4 waves = 4096 blocks.
__global__ __launch_bounds__(256) void poolA_kernel(
    const float* __restrict__ rgb, const float* __restrict__ dep,
    float* __restrict__ nodes /* [32][4][256] */)
{
    const int rw   = blockIdx.x * 4 + (threadIdx.x >> 6);  // 0..16383
    const int lane = threadIdx.x & 63;
    const int tensor = rw >> 13;              // 0 = rgb, 1 = dep
    const int row    = rw & 8191;             // b*256 + c
    const f4* src = (const f4*)((tensor ? dep : rgb) + (size_t)row * 4096);

    f4 v[8];
    f4 acc = {0.f, 0.f, 0.f, 0.f};
#pragma unroll
    for (int j = 0; j < 8; ++j) v[j] = __builtin_nontemporal_load(src + lane + 64 * j);
#pragma unroll
    for (int j = 0; j < 8; ++j) acc += v[j];
#pragma unroll
    for (int j = 0; j < 8; ++j) v[j] = __builtin_nontemporal_load(src + lane + 64 * (8 + j));
#pragma unroll
    for (int j = 0; j < 8; ++j) acc += v[j];

    float s = acc.x + acc.y + acc.z + acc.w;
#pragma unroll
    for (int off = 32; off; off >>= 1) s += __shfl_down(s, off, 64);
    if (lane == 0) {
        const int b = row >> 8, c = row & 255;
        nodes[(size_t)b * 1024 + (2 + tensor) * CCH + c] = s * (1.f / 4096.f);
    }
}

// ---------------- Kernel 1b: pool x_ful (temporal — keep in L3 for apply) ----------------
__global__ __launch_bounds__(256) void poolB_kernel(
    const float* __restrict__ xf, float* __restrict__ nodes)
{
    const int row  = blockIdx.x * 4 + (threadIdx.x >> 6);  // 0..8191
    const int lane = threadIdx.x & 63;
    const f4* src = (const f4*)(xf + (size_t)row * 4096);

    f4 v[8];
    f4 acc = {0.f, 0.f, 0.f, 0.f};
#pragma unroll
    for (int j = 0; j < 8; ++j) v[j] = src[lane + 64 * j];
#pragma unroll
    for (int j = 0; j < 8; ++j) acc += v[j];
#pragma unroll
    for (int j = 0; j < 8; ++j) v[j] = src[lane + 64 * (8 + j)];
#pragma unroll
    for (int j = 0; j < 8; ++j) acc += v[j];

    float s = acc.x + acc.y + acc.z + acc.w;
#pragma unroll
    for (int off = 32; off; off >>= 1) s += __shfl_down(s, off, 64);
    if (lane == 0) {
        const int b = row >> 8, c = row & 255;
        nodes[(size_t)b * 1024 + 1 * CCH + c] = s * (1.f / 4096.f);
    }
}

// ---------------- Kernel 2: 2x (GATConv + residual + LN + ReLU), output gate ----------------
// grid: 32 blocks (batch), 1024 threads: t = h*256 + c.
__global__ __launch_bounds__(1024) void gat_kernel(
    const float* __restrict__ nodes, const float* __restrict__ tok,
    float* __restrict__ scale,
    const float* __restrict__ W0, const float* __restrict__ as0,
    const float* __restrict__ ad0, const float* __restrict__ b0,
    const float* __restrict__ g0, const float* __restrict__ be0,
    const float* __restrict__ W1, const float* __restrict__ as1,
    const float* __restrict__ ad1, const float* __restrict__ b1,
    const float* __restrict__ g1, const float* __restrict__ be1)
{
    const int t = threadIdx.x;          // 0..1023
    const int b = blockIdx.x;
    const int h = t >> 8, c = t & 255;

    __shared__ float gl[4][CCH];        // node features
    __shared__ float xp[4][HEADS * CCH];// xp[n][h*256+c] (also reused for head sums)
    __shared__ float red2[16][2];
    __shared__ float es[4][4], ed[4][4];      // [n][h]
    __shared__ float alpha_s[4][4][4];        // [d][h][j]
    __shared__ float mu_s[4], rstd_s[4];

    gl[t >> 8][t & 255] = (t < 256) ? tok[t] : nodes[(size_t)b * 1024 + t];
    __syncthreads();

    for (int layer = 0; layer < 2; ++layer) {
        const float* W  = layer ? W1  : W0;
        const float* As = layer ? as1 : as0;
        const float* Ad = layer ? ad1 : ad0;
        const float* Bi = layer ? b1  : b0;
        const float* Ga = layer ? g1  : g0;
        const float* Be = layer ? be1 : be0;

        // ---- xp = x @ W : thread t owns column t (= h*256+c) for all 4 nodes
        float a0 = 0.f, a1 = 0.f, a2 = 0.f, a3 = 0.f;
#pragma unroll 4
        for (int k = 0; k < 256; ++k) {
            float w = W[k * 1024 + t];
            a0 += gl[0][k] * w;
            a1 += gl[1][k] * w;
            a2 += gl[2][k] * w;
            a3 += gl[3][k] * w;
        }
        xp[0][t] = a0; xp[1][t] = a1; xp[2][t] = a2; xp[3][t] = a3;
        __syncthreads();

        // ---- attention logits: e_src[n][h], e_dst[n][h]
        const float av = As[t];   // a_src[h][c] flat == t
        const float dv = Ad[t];
#pragma unroll
        for (int n = 0; n < 4; ++n) {
            float x = xp[n][t];
            float vs = x * av, vd = x * dv;
#pragma unroll
            for (int off = 32; off; off >>= 1) {
                vs += __shfl_down(vs, off, 64);
                vd += __shfl_down(vd, off, 64);
            }
            if ((t & 63) == 0) { red2[t >> 6][0] = vs; red2[t >> 6][1] = vd; }
            __syncthreads();
            if (t < 4) {   // t = head
                es[n][t] = red2[t*4][0] + red2[t*4+1][0] + red2[t*4+2][0] + red2[t*4+3][0];
                ed[n][t] = red2[t*4][1] + red2[t*4+1][1] + red2[t*4+2][1] + red2[t*4+3][1];
            }
            __syncthreads();
        }

        // ---- per-destination segment softmax (16 threads: d*4+h)
        if (t < 16) {
            const int d = t >> 2, hh = t & 3;
            const int cnt[4]        = {4, 3, 3, 3};
            const int srcs[4][4]    = {{1,2,3,0},{2,3,1,0},{1,3,2,0},{1,2,3,0}};
            float v[4];
            float m = -1e30f;
            const int n = cnt[d];
            for (int j = 0; j < n; ++j) {
                float e = es[srcs[d][j]][hh] + ed[d][hh];
                e = (e >= 0.f) ? e : 0.2f * e;         // leaky_relu 0.2
                v[j] = e; m = fmaxf(m, e);
            }
            float den = 0.f;
            for (int j = 0; j < n; ++j) { v[j] = expf(v[j] - m); den += v[j]; }
            float inv = 1.f / den;
            for (int j = 0; j < n; ++j) alpha_s[d][hh][j] = v[j] * inv;
            for (int j = n; j < 4; ++j) alpha_s[d][hh][j] = 0.f;
        }
        __syncthreads();

        // ---- aggregate messages: per-thread (h,c), all 4 dst nodes
        float ms[4];
        {
            const int srcs[4][4] = {{1,2,3,0},{2,3,1,0},{1,3,2,0},{1,2,3,0}};
#pragma unroll
            for (int d = 0; d < 4; ++d) {
                float s = 0.f;
#pragma unroll
                for (int j = 0; j < 4; ++j)
                    s += alpha_s[d][h][j] * xp[srcs[d][j]][t];
                ms[d] = s;
            }
        }
        __syncthreads();
#pragma unroll
        for (int d = 0; d < 4; ++d) xp[d][t] = ms[d];   // xp now holds per-head sums
        __syncthreads();

        // ---- head mean + bias + residual + LayerNorm + ReLU; thread t = (d = t>>8, c)
        const int d = t >> 8;
        float o = 0.25f * (xp[d][c] + xp[d][256 + c] + xp[d][512 + c] + xp[d][768 + c]) + Bi[c];
        float gv = o + gl[d][c];                        // residual
        float vs = gv, vq = gv * gv;
#pragma unroll
        for (int off = 32; off; off >>= 1) {
            vs += __shfl_down(vs, off, 64);
            vq += __shfl_down(vq, off, 64);
        }
        if ((t & 63) == 0) { red2[t >> 6][0] = vs; red2[t >> 6][1] = vq; }
        __syncthreads();
        if (t < 4) {
            float s = red2[t*4][0] + red2[t*4+1][0] + red2[t*4+2][0] + red2[t*4+3][0];
            float q = red2[t*4][1] + red2[t*4+1][1] + red2[t*4+2][1] + red2[t*4+3][1];
            float mu  = s * (1.f / 256.f);
            float var = q * (1.f / 256.f) - mu * mu;
            mu_s[t]   = mu;
            rstd_s[t] = rsqrtf(var + 1e-5f);
        }
        __syncthreads();
        float y = (gv - mu_s[d]) * rstd_s[d] * Ga[c] + Be[c];
        y = fmaxf(y, 0.f);
        gl[d][c] = y;
        __syncthreads();
    }

    // ---- output gate from token node: scale = 1 + sigmoid(g[b,0,c])
    if (t < 256) {
        float x = gl[0][t];
        float sg = 1.f / (1.f + expf(-x));
        scale[(size_t)b * CCH + t] = 1.f + sg;
    }
}

// ---------------- Kernel 3: out = x_ful * (1 + sigmoid), nontemporal store ----------------
__global__ __launch_bounds__(256) void apply_kernel(
    const float* __restrict__ xf, const float* __restrict__ scale,
    float* __restrict__ out, int total4)
{
    int idx = blockIdx.x * 256 + threadIdx.x;
    const int stride = gridDim.x * 256;
    const f4* in4 = (const f4*)xf;
    f4* out4 = (f4*)out;
    for (; idx < total4; idx += stride) {
        f4 v = in4[idx];
        const float s = scale[idx >> 10];          // 1024 float4 per (b,c) row
        f4 o = v * s;
        __builtin_nontemporal_store(o, out4 + idx);
    }
}

extern "C" void kernel_launch(void* const* d_in, const int* in_sizes, int n_in,
                              void* d_out, int out_size, void* d_ws, size_t ws_size,
                              hipStream_t stream) {
    const float* x_ful = (const float*)d_in[0];
    const float* rgb   = (const float*)d_in[1];
    const float* dep   = (const float*)d_in[2];
    const float* tok   = (const float*)d_in[3];
    const float* W0  = (const float*)d_in[4];
    const float* as0 = (const float*)d_in[5];
    const float* ad0 = (const float*)d_in[6];
    const float* b0  = (const float*)d_in[7];
    const float* g0  = (const float*)d_in[8];
    const float* be0 = (const float*)d_in[9];
    const float* W1  = (const float*)d_in[10];
    const float* as1 = (const float*)d_in[11];
    const float* ad1 = (const float*)d_in[12];
    const float* b1  = (const float*)d_in[13];
    const float* g1  = (const float*)d_in[14];
    const float* be1 = (const float*)d_in[15];

    float* nodes = (float*)d_ws;                          // [32][4][256] = 128 KB
    float* scale = (float*)((char*)d_ws + 32 * 4 * CCH * sizeof(float)); // [32][256]
    float* out   = (float*)d_out;

    // rgb+dep first (nontemporal), x_ful last (temporal -> L3-resident for apply)
    poolA_kernel<<<4096, 256, 0, stream>>>(rgb, dep, nodes);
    poolB_kernel<<<2048, 256, 0, stream>>>(x_ful, nodes);
    gat_kernel<<<32, 1024, 0, stream>>>(nodes, tok, scale,
                                        W0, as0, ad0, b0, g0, be0,
                                        W1, as1, ad1, b1, g1, be1);
    const int total4 = 32 * CCH * 64 * 64 / 4;            // 8,388,608 float4
    apply_kernel<<<2048, 256, 0, stream>>>(x_ful, scale, out, total4);
}

// Round 3
// 154.265 us; speedup vs baseline: 1.3594x; 1.0795x over previous
//
#include <hip/hip_runtime.h>
#include <hip/hip_bf16.h>

#define CCH 256
#define HEADS 4

typedef float f4 __attribute__((ext_vector_type(4)));

// ---------------- Kernel 1a: pool rgb + dep (nontemporal loads) ----------------
// wave-per-row: 64 lanes x 16 float4 = 4096 floats. grid = 16384 rows / 4 waves = 4096 blocks.
__global__ __launch_bounds__(256) void poolA_kernel(
    const float* __restrict__ rgb, const float* __restrict__ dep,
    float* __restrict__ nodes /* [32][4][256] */)
{
    const int rw   = blockIdx.x * 4 + (threadIdx.x >> 6);  // 0..16383
    const int lane = threadIdx.x & 63;
    const int tensor = rw >> 13;              // 0 = rgb, 1 = dep
    const int row    = rw & 8191;             // b*256 + c
    const f4* src = (const f4*)((tensor ? dep : rgb) + (size_t)row * 4096);

    f4 v[8];
    f4 acc = {0.f, 0.f, 0.f, 0.f};
#pragma unroll
    for (int j = 0; j < 8; ++j) v[j] = __builtin_nontemporal_load(src + lane + 64 * j);
#pragma unroll
    for (int j = 0; j < 8; ++j) acc += v[j];
#pragma unroll
    for (int j = 0; j < 8; ++j) v[j] = __builtin_nontemporal_load(src + lane + 64 * (8 + j));
#pragma unroll
    for (int j = 0; j < 8; ++j) acc += v[j];

    float s = acc.x + acc.y + acc.z + acc.w;
#pragma unroll
    for (int off = 32; off; off >>= 1) s += __shfl_down(s, off, 64);
    if (lane == 0) {
        const int b = row >> 8, c = row & 255;
        nodes[(size_t)b * 1024 + (2 + tensor) * CCH + c] = s * (1.f / 4096.f);
    }
}

// ---------------- Kernel 1b: pool x_ful (temporal — keep in L3 for apply) ----------------
__global__ __launch_bounds__(256) void poolB_kernel(
    const float* __restrict__ xf, float* __restrict__ nodes)
{
    const int row  = blockIdx.x * 4 + (threadIdx.x >> 6);  // 0..8191
    const int lane = threadIdx.x & 63;
    const f4* src = (const f4*)(xf + (size_t)row * 4096);

    f4 v[8];
    f4 acc = {0.f, 0.f, 0.f, 0.f};
#pragma unroll
    for (int j = 0; j < 8; ++j) v[j] = src[lane + 64 * j];
#pragma unroll
    for (int j = 0; j < 8; ++j) acc += v[j];
#pragma unroll
    for (int j = 0; j < 8; ++j) v[j] = src[lane + 64 * (8 + j)];
#pragma unroll
    for (int j = 0; j < 8; ++j) acc += v[j];

    float s = acc.x + acc.y + acc.z + acc.w;
#pragma unroll
    for (int off = 32; off; off >>= 1) s += __shfl_down(s, off, 64);
    if (lane == 0) {
        const int b = row >> 8, c = row & 255;
        nodes[(size_t)b * 1024 + 1 * CCH + c] = s * (1.f / 4096.f);
    }
}

// ---------------- Kernel 2: 2x (GATConv + residual + LN + ReLU), output gate ----------------
// grid: 32 blocks (batch), 256 threads (t = channel). Thread t owns columns
// {h*256+t, h=0..3} x 4 nodes => acc[4][4] stays in registers through the
// whole layer (logits, softmax-agg, head-mean, residual, LN).
__global__ __launch_bounds__(256) void gat_kernel(
    const float* __restrict__ nodes, const float* __restrict__ tok,
    float* __restrict__ scale,
    const float* __restrict__ W0, const float* __restrict__ as0,
    const float* __restrict__ ad0, const float* __restrict__ b0,
    const float* __restrict__ g0, const float* __restrict__ be0,
    const float* __restrict__ W1, const float* __restrict__ as1,
    const float* __restrict__ ad1, const float* __restrict__ b1,
    const float* __restrict__ g1, const float* __restrict__ be1)
{
    const int t = threadIdx.x;          // channel c, 0..255
    const int b = blockIdx.x;
    const int lane = t & 63, wv = t >> 6;

    __shared__ float gl[4][CCH];        // node features (current layer input)
    __shared__ float redl[4][32];       // per-wave partials: 16 src + 16 dst
    __shared__ float esed[32];          // [n*4+h] es ; [16+n*4+h] ed
    __shared__ float alpha_s[4][4][4];  // [dst][head][src-slot]
    __shared__ float red2[4][8];        // per-wave LN partials
    __shared__ float mu_s[4], rstd_s[4];

    gl[0][t] = tok[t];
    gl[1][t] = nodes[(size_t)b * 1024 + 256 + t];
    gl[2][t] = nodes[(size_t)b * 1024 + 512 + t];
    gl[3][t] = nodes[(size_t)b * 1024 + 768 + t];
    __syncthreads();

    for (int layer = 0; layer < 2; ++layer) {
        const float* W  = layer ? W1  : W0;
        const float* As = layer ? as1 : as0;
        const float* Ad = layer ? ad1 : ad0;
        const float* Bi = layer ? b1  : b0;
        const float* Ga = layer ? g1  : g0;
        const float* Be = layer ? be1 : be0;

        // ---- xp = x @ W : acc[j=head][n=node], 8-deep register-staged k-loop
        float acc[4][4];
#pragma unroll
        for (int j = 0; j < 4; ++j)
#pragma unroll
            for (int n = 0; n < 4; ++n) acc[j][n] = 0.f;

        const float* Wp = W + t;
        for (int k0 = 0; k0 < 256; k0 += 8) {
            float wr[8][4];
#pragma unroll
            for (int u = 0; u < 8; ++u)
#pragma unroll
                for (int j = 0; j < 4; ++j)
                    wr[u][j] = Wp[(k0 + u) * 1024 + j * 256];
#pragma unroll
            for (int u = 0; u < 8; ++u) {
                float g0v = gl[0][k0 + u], g1v = gl[1][k0 + u];
                float g2v = gl[2][k0 + u], g3v = gl[3][k0 + u];
#pragma unroll
                for (int j = 0; j < 4; ++j) {
                    float w = wr[u][j];
                    acc[j][0] += g0v * w;
                    acc[j][1] += g1v * w;
                    acc[j][2] += g2v * w;
                    acc[j][3] += g3v * w;
                }
            }
        }

        // ---- attention logits: 32 simultaneous reductions over c
        float asr[4], adr[4];
#pragma unroll
        for (int j = 0; j < 4; ++j) { asr[j] = As[j * 256 + t]; adr[j] = Ad[j * 256 + t]; }
        float rv[32];
#pragma unroll
        for (int n = 0; n < 4; ++n)
#pragma unroll
            for (int j = 0; j < 4; ++j) {
                rv[n * 4 + j]      = acc[j][n] * asr[j];
                rv[16 + n * 4 + j] = acc[j][n] * adr[j];
            }
#pragma unroll
        for (int i = 0; i < 32; ++i)
#pragma unroll
            for (int off = 32; off; off >>= 1)
                rv[i] += __shfl_down(rv[i], off, 64);
        if (lane == 0) {
#pragma unroll
            for (int i = 0; i < 32; ++i) redl[wv][i] = rv[i];
        }
        __syncthreads();
        if (t < 32) esed[t] = redl[0][t] + redl[1][t] + redl[2][t] + redl[3][t];
        __syncthreads();

        // ---- per-destination segment softmax (16 threads: d*4+h)
        if (t < 16) {
            const int d = t >> 2, hh = t & 3;
            const int cnt[4]     = {4, 3, 3, 3};
            const int srcs[4][4] = {{1,2,3,0},{2,3,1,0},{1,3,2,0},{1,2,3,0}};
            float v[4];
            float m = -1e30f;
            const int n = cnt[d];
            for (int s = 0; s < n; ++s) {
                float e = esed[srcs[d][s] * 4 + hh] + esed[16 + d * 4 + hh];
                e = (e >= 0.f) ? e : 0.2f * e;         // leaky_relu 0.2
                v[s] = e; m = fmaxf(m, e);
            }
            float den = 0.f;
            for (int s = 0; s < n; ++s) { v[s] = expf(v[s] - m); den += v[s]; }
            float inv = 1.f / den;
            for (int s = 0; s < n; ++s) alpha_s[d][hh][s] = v[s] * inv;
            for (int s = n; s < 4; ++s) alpha_s[d][hh][s] = 0.f;
        }
        __syncthreads();

        // ---- aggregate + head mean + bias + residual (all in registers)
        const int srcs2[4][4] = {{1,2,3,0},{2,3,1,0},{1,3,2,0},{1,2,3,0}};
        float bi = Bi[t];
        float gv[4];
#pragma unroll
        for (int d = 0; d < 4; ++d) {
            float sum = 0.f;
#pragma unroll
            for (int j = 0; j < 4; ++j) {
                float mj = 0.f;
#pragma unroll
                for (int s = 0; s < 4; ++s)
                    mj += alpha_s[d][j][s] * acc[j][srcs2[d][s]];
                sum += mj;
            }
            gv[d] = 0.25f * sum + bi + gl[d][t];
        }

        // ---- LayerNorm: 8 simultaneous reductions (sum, sumsq per node)
        float rv2[8];
#pragma unroll
        for (int d = 0; d < 4; ++d) { rv2[d * 2] = gv[d]; rv2[d * 2 + 1] = gv[d] * gv[d]; }
#pragma unroll
        for (int i = 0; i < 8; ++i)
#pragma unroll
            for (int off = 32; off; off >>= 1)
                rv2[i] += __shfl_down(rv2[i], off, 64);
        if (lane == 0) {
#pragma unroll
            for (int i = 0; i < 8; ++i) red2[wv][i] = rv2[i];
        }
        __syncthreads();
        if (t < 4) {
            float s = red2[0][t*2]   + red2[1][t*2]   + red2[2][t*2]   + red2[3][t*2];
            float q = red2[0][t*2+1] + red2[1][t*2+1] + red2[2][t*2+1] + red2[3][t*2+1];
            float mu  = s * (1.f / 256.f);
            float var = q * (1.f / 256.f) - mu * mu;
            mu_s[t]   = mu;
            rstd_s[t] = rsqrtf(var + 1e-5f);
        }
        __syncthreads();
        float ga = Ga[t], be = Be[t];
#pragma unroll
        for (int d = 0; d < 4; ++d) {
            float y = (gv[d] - mu_s[d]) * rstd_s[d] * ga + be;
            gl[d][t] = fmaxf(y, 0.f);
        }
        __syncthreads();
    }

    // ---- output gate from token node: scale = 1 + sigmoid(g[b,0,c])
    float x = gl[0][t];
    scale[(size_t)b * CCH + t] = 1.f + 1.f / (1.f + expf(-x));
}

// ---------------- Kernel 3: out = x_ful * (1 + sigmoid), nontemporal store ----------------
__global__ __launch_bounds__(256) void apply_kernel(
    const float* __restrict__ xf, const float* __restrict__ scale,
    float* __restrict__ out, int total4)
{
    int idx = blockIdx.x * 256 + threadIdx.x;
    const int stride = gridDim.x * 256;
    const f4* in4 = (const f4*)xf;
    f4* out4 = (f4*)out;
    for (; idx < total4; idx += stride) {
        f4 v = in4[idx];
        const float s = scale[idx >> 10];          // 1024 float4 per (b,c) row
        f4 o = v * s;
        __builtin_nontemporal_store(o, out4 + idx);
    }
}

extern "C" void kernel_launch(void* const* d_in, const int* in_sizes, int n_in,
                              void* d_out, int out_size, void* d_ws, size_t ws_size,
                              hipStream_t stream) {
    const float* x_ful = (const float*)d_in[0];
    const float* rgb   = (const float*)d_in[1];
    const float* dep   = (const float*)d_in[2];
    const float* tok   = (const float*)d_in[3];
    const float* W0  = (const float*)d_in[4];
    const float* as0 = (const float*)d_in[5];
    const float* ad0 = (const float*)d_in[6];
    const float* b0  = (const float*)d_in[7];
    const float* g0  = (const float*)d_in[8];
    const float* be0 = (const float*)d_in[9];
    const float* W1  = (const float*)d_in[10];
    const float* as1 = (const float*)d_in[11];
    const float* ad1 = (const float*)d_in[12];
    const float* b1  = (const float*)d_in[13];
    const float* g1  = (const float*)d_in[14];
    const float* be1 = (const float*)d_in[15];

    float* nodes = (float*)d_ws;                          // [32][4][256] = 128 KB
    float* scale = (float*)((char*)d_ws + 32 * 4 * CCH * sizeof(float)); // [32][256]
    float* out   = (float*)d_out;

    // rgb+dep first (nontemporal), x_ful last (temporal -> L3-resident for apply)
    poolA_kernel<<<4096, 256, 0, stream>>>(rgb, dep, nodes);
    poolB_kernel<<<2048, 256, 0, stream>>>(x_ful, nodes);
    gat_kernel<<<32, 256, 0, stream>>>(nodes, tok, scale,
                                       W0, as0, ad0, b0, g0, be0,
                                       W1, as1, ad1, b1, g1, be1);
    const int total4 = 32 * CCH * 64 * 64 / 4;            // 8,388,608 float4
    apply_kernel<<<2048, 256, 0, stream>>>(x_ful, scale, out, total4);
}